// Round 11
// baseline (2548.058 us; speedup 1.0000x reference)
//
#include <hip/hip_runtime.h>

typedef unsigned int   uint;
typedef unsigned short ushort;
typedef unsigned long long u64;
typedef float f32x4 __attribute__((ext_vector_type(4)));

// weights loaded once (from LDS), applied to two rows
__device__ __forceinline__ void dot16x2(const float* __restrict__ wr,
                                        const f32x4* xa, const f32x4* xb,
                                        float& accA, float& accB){
#pragma unroll
  for (int k=0;k<4;k++){
    f32x4 w=*(const f32x4*)(wr+4*k);
    accA=fmaf(xa[k][0],w[0],accA); accA=fmaf(xa[k][1],w[1],accA);
    accA=fmaf(xa[k][2],w[2],accA); accA=fmaf(xa[k][3],w[3],accA);
    accB=fmaf(xb[k][0],w[0],accB); accB=fmaf(xb[k][1],w[1],accB);
    accB=fmaf(xb[k][2],w[2],accB); accB=fmaf(xb[k][3],w[3],accB);
  }
}

// ---------------------------------------------------------------- fused FPS + KNN
// r21: fps uses 16 CUs for ~755us while 240 idle; knn depends only on cent[b].
// Fuse into ONE kernel: blocks 0-15 run fps (r13 body verbatim) and publish a
// per-batch flag via device-scope release; blocks 16-511 run knn units (r20
// body verbatim), acquire-spinning on their batch's flag. grid=512 with
// <=2 blocks/CU (LDS 69.7KB, VGPR<=112 via launch_bounds) -> ALL blocks
// co-resident -> spin cannot deadlock. Flags zeroed by hipMemsetAsync;
// producer+consumer share the dispatch, so isolated counter-replay cannot
// hang (stale flags only cause early start with masked indices).
__global__ __launch_bounds__(256,2) void k_fk(const float* __restrict__ xyz,
                                              int* __restrict__ cent,
                                              float* __restrict__ oxyz,
                                              ushort* __restrict__ kidx,
                                              int* __restrict__ flags){
  __shared__ __align__(16) char LU[69760];
  const int bid=blockIdx.x, tid=threadIdx.x, lane=tid&63, wave=tid>>6;

  if (bid < 16){
    // ---------------- FPS (r13, measured best) ----------------
    float (*sp)[4] = (float(*)[4])LU;            // 64 KB
    u64* rk  = (u64*)(LU + 65536);               // 2*4 u64
    int* sel = (int*)(LU + 65600);               // 4 KB -> ends 69696
    const int b = bid;
    const float* xb = xyz + (long)b*4096*3;
    float px[16], py[16], pz[16], pd[16];
#pragma unroll
    for (int j=0;j<16;j++){
      int n = tid + 256*j;
      float x=xb[n*3], y=xb[n*3+1], z=xb[n*3+2];
      sp[n][0]=x; sp[n][1]=y; sp[n][2]=z; sp[n][3]=0.0f;
      px[j]=x; py[j]=y; pz[j]=z; pd[j]=1e10f;
    }
    if (tid==0) sel[0]=0;
    __syncthreads();
    int f = 0;
    for (int t=1;t<1024;t++){
      f32x4 c = *(const f32x4*)sp[f];
      float bv=-1.0f; int bi=0;
#pragma unroll
      for (int j=0;j<16;j++){
        int n = tid + 256*j;
        float dx=px[j]-c[0], dy=py[j]-c[1], dz=pz[j]-c[2];
        float d=__fadd_rn(__fadd_rn(__fmul_rn(dx,dx),__fmul_rn(dy,dy)),__fmul_rn(dz,dz));
        float mn=fminf(pd[j],d); pd[j]=mn;
        if (j==0){ bv=mn; bi=n; }
        else if (mn>bv){ bv=mn; bi=n; }
      }
      u64 key = ((u64)__float_as_uint(bv)<<32) | (uint)(~bi);
#pragma unroll
      for (int off=32;off;off>>=1){
        u64 ok=__shfl_xor(key,off);
        key = ok>key ? ok : key;
      }
      int par=t&1;
      if (lane==0) rk[par*4+wave]=key;
      __syncthreads();
      {
        u64 k0=rk[par*4+0], k1=rk[par*4+1], k2=rk[par*4+2], k3=rk[par*4+3];
        u64 ka = k0>k1?k0:k1;
        u64 kb = k2>k3?k2:k3;
        u64 kk = ka>kb?ka:kb;
        f = (int)(~(uint)kk) & 4095;
      }
      if (tid==0) sel[t]=f;
    }
    __syncthreads();
#pragma unroll
    for (int j=0;j<4;j++){
      int s = tid + 256*j;
      int n = sel[s];
      cent[b*1024+s]=n;
      f32x4 cf=*(const f32x4*)sp[n];
      oxyz[(b*1024+s)*3+0]=cf[0];
      oxyz[(b*1024+s)*3+1]=cf[1];
      oxyz[(b*1024+s)*3+2]=cf[2];
    }
    __threadfence();                 // per-thread device-scope fence
    __syncthreads();
    if (tid==0)
      __hip_atomic_store(&flags[b], 1, __ATOMIC_RELEASE, __HIP_MEMORY_SCOPE_AGENT);
  } else {
    // ---------------- KNN (r20 body) ----------------
    float* sx=(float*)LU; float* sy=sx+4096; float* sz=sy+4096;   // 48 KB
    for (int u = bid-16; u < 512; u += 496){
      const int b = u>>5, chunk = u&31;
      if (tid==0){
        while (__hip_atomic_load(&flags[b], __ATOMIC_ACQUIRE, __HIP_MEMORY_SCOPE_AGENT)==0)
          __builtin_amdgcn_s_sleep(64);
      }
      __syncthreads();   // flag visible to block; also fences LDS re-stage
      const float* xb = xyz + (long)b*4096*3;
#pragma unroll
      for (int j=0;j<16;j++){
        int n = tid + 256*j;
        sx[n]=xb[n*3]; sy[n]=xb[n*3+1]; sz[n]=xb[n*3+2];
      }
      __syncthreads();
      const u64 SENT=~0ull;
      for (int qi=0; qi<8; qi++){
        int s = chunk*32 + wave*8 + qi;
        int qn = cent[b*1024 + s] & 4095;
        double qx=(double)sx[qn], qy=(double)sy[qn], qz=(double)sz[qn];
        u64 k1=SENT, k2=SENT;
#pragma unroll 8
        for (int j=0;j<64;j++){
          int n = lane + 64*j;
          double dx=(double)sx[n]-qx, dy=(double)sy[n]-qy, dz=(double)sz[n]-qz;
          double d2 = dx*dx + dy*dy + dz*dz;
          u64 kd = (((u64)__double_as_longlong(d2)) & ~4095ull) | (uint)n;
          if (kd<k1){ k2=k1; k1=kd; }
          else if (kd<k2){ k2=kd; }
        }
        u64 removed=0ull;
        ushort* outp = kidx + (b*1024 + s)*32;
        for (int r=0;r<32;r++){
          u64 wk=k1;
#pragma unroll
          for (int off=32;off;off>>=1){
            u64 ok=__shfl_xor(wk,off);
            wk = ok<wk ? ok : wk;
          }
          if (lane==0) outp[r]=(ushort)(wk & 4095u);
          if (wk==k1){
            removed |= 1ull << (((uint)(k1&4095u))>>6);
            if (k2!=SENT){ k1=k2; k2=SENT; }
            else {
              k1=SENT; k2=SENT;
#pragma unroll 8
              for (int j=0;j<64;j++){
                if ((removed>>j)&1ull) continue;
                int n = lane + 64*j;
                double dx=(double)sx[n]-qx, dy=(double)sy[n]-qy, dz=(double)sz[n]-qz;
                double d2 = dx*dx + dy*dy + dz*dz;
                u64 kd = (((u64)__double_as_longlong(d2)) & ~4095ull) | (uint)n;
                if (kd<k1){ k2=k1; k1=kd; }
                else if (kd<k2){ k2=kd; }
              }
            }
          }
        }
      }
      __syncthreads();   // all done with sx/sy/sz before next unit restages
    }
  }
}

// ================================================================ MLP passes (r20, passing)
// pass 1: gather -> L1 -> stats + store raw y1
__global__ __launch_bounds__(256) void k_mlp1b(const float* __restrict__ xyz,
                                               const float* __restrict__ pts,
                                               const float* __restrict__ w1,
                                               const float* __restrict__ b1,
                                               const int* __restrict__ cent,
                                               const ushort* __restrict__ kidx,
                                               float* __restrict__ part,
                                               float* __restrict__ y){
  __shared__ __align__(16) float L[9760];   // W1 4384 | XIN 4352 | WRED 1024
  float* W1  = L;
  float* XIN = L+4384;
  float* WRED= L+8736;
  const int tid=threadIdx.x, bi=blockIdx.x;
  const int row=tid>>3, oc=tid&7, wave=tid>>6;
  const int b=bi>>6, s0=(bi&63)*16;
  const long bN=(long)b*4096;

  for (int i=tid;i<64*68;i+=256){
    int r=i/68, c=i-r*68;
    float v = (c<64)? w1[r*67+3+c] : (c<67? w1[r*67+(c-64)] : 0.0f);
    W1[r*68+((r>>3)<<2)+c]=v;
  }
  float breg1[8];
#pragma unroll
  for (int i=0;i<8;i++) breg1[i]=b1[oc*8+i];
  float ps[8], pq[8];
#pragma unroll
  for (int s=0;s<8;s++){ ps[s]=0.f; pq[s]=0.f; }
  __syncthreads();

  for (int t=0; t<8; t++){
    int sgA = b*1024 + s0 + t*2, sgB = sgA+1;
    {
      int nA = kidx[sgA*32+row] & 4095;
      int nB = kidx[sgB*32+row] & 4095;
      const float* prA = pts + (bN+nA)*64;
      const float* prB = pts + (bN+nB)*64;
      *(f32x4*)(XIN + row*68 + oc*8)          = *(const f32x4*)(prA + oc*8);
      *(f32x4*)(XIN + row*68 + oc*8 + 4)      = *(const f32x4*)(prA + oc*8 + 4);
      *(f32x4*)(XIN + (row+32)*68 + oc*8)     = *(const f32x4*)(prB + oc*8);
      *(f32x4*)(XIN + (row+32)*68 + oc*8 + 4) = *(const f32x4*)(prB + oc*8 + 4);
      if (oc==0){
        int qA = cent[sgA] & 4095, qB = cent[sgB] & 4095;
        const float* xpA = xyz + (bN+nA)*3; const float* qpA = xyz + (bN+qA)*3;
        const float* xpB = xyz + (bN+nB)*3; const float* qpB = xyz + (bN+qB)*3;
        XIN[row*68+64]=xpA[0]-qpA[0]; XIN[row*68+65]=xpA[1]-qpA[1];
        XIN[row*68+66]=xpA[2]-qpA[2]; XIN[row*68+67]=0.0f;
        XIN[(row+32)*68+64]=xpB[0]-qpB[0]; XIN[(row+32)*68+65]=xpB[1]-qpB[1];
        XIN[(row+32)*68+66]=xpB[2]-qpB[2]; XIN[(row+32)*68+67]=0.0f;
      }
    }
    const float* xrowA = XIN + row*68;
    const float* xrowB = XIN + (row+32)*68;
    float acc[2][8];
#pragma unroll
    for (int i=0;i<8;i++){ acc[0][i]=breg1[i]; acc[1][i]=breg1[i]; }
#pragma unroll
    for (int co=0;co<4;co++){
      f32x4 xa[4], xbv[4];
#pragma unroll
      for (int k=0;k<4;k++){ xa[k]=*(const f32x4*)(xrowA+co*16+4*k); xbv[k]=*(const f32x4*)(xrowB+co*16+4*k); }
#pragma unroll
      for (int i=0;i<8;i++)
        dot16x2(W1+(oc*8+i)*68+(oc<<2)+co*16, xa, xbv, acc[0][i], acc[1][i]);
    }
    {
      f32x4 xtA=*(const f32x4*)(xrowA+64), xtB=*(const f32x4*)(xrowB+64);
#pragma unroll
      for (int i=0;i<8;i++){
        const float* wr=W1+(oc*8+i)*68+(oc<<2)+64;
        f32x4 w=*(const f32x4*)wr;
        acc[0][i]=fmaf(xtA[0],w[0],acc[0][i]); acc[0][i]=fmaf(xtA[1],w[1],acc[0][i]);
        acc[0][i]=fmaf(xtA[2],w[2],acc[0][i]); acc[0][i]=fmaf(xtA[3],w[3],acc[0][i]);
        acc[1][i]=fmaf(xtB[0],w[0],acc[1][i]); acc[1][i]=fmaf(xtB[1],w[1],acc[1][i]);
        acc[1][i]=fmaf(xtB[2],w[2],acc[1][i]); acc[1][i]=fmaf(xtB[3],w[3],acc[1][i]);
      }
    }
    // store raw y1 + stats
    {
      long baseA = ((long)sgA*32+row)*64 + oc*8;
      long baseB = ((long)sgB*32+row)*64 + oc*8;
      *(f32x4*)(y+baseA)   = (f32x4){acc[0][0],acc[0][1],acc[0][2],acc[0][3]};
      *(f32x4*)(y+baseA+4) = (f32x4){acc[0][4],acc[0][5],acc[0][6],acc[0][7]};
      *(f32x4*)(y+baseB)   = (f32x4){acc[1][0],acc[1][1],acc[1][2],acc[1][3]};
      *(f32x4*)(y+baseB+4) = (f32x4){acc[1][4],acc[1][5],acc[1][6],acc[1][7]};
    }
#pragma unroll
    for (int i=0;i<8;i++){
      ps[i]+=acc[0][i]+acc[1][i];
      pq[i]=fmaf(acc[0][i],acc[0][i],pq[i]); pq[i]=fmaf(acc[1][i],acc[1][i],pq[i]);
    }
  }
#pragma unroll
  for (int s=0;s<8;s++){
    ps[s]+=__shfl_xor(ps[s],8); ps[s]+=__shfl_xor(ps[s],16); ps[s]+=__shfl_xor(ps[s],32);
    pq[s]+=__shfl_xor(pq[s],8); pq[s]+=__shfl_xor(pq[s],16); pq[s]+=__shfl_xor(pq[s],32);
  }
  __syncthreads();
  if ((tid&63)<8){
    for (int s=0;s<8;s++){
      WRED[((wave*8+oc)*16+s)*2+0]=ps[s];
      WRED[((wave*8+oc)*16+s)*2+1]=pq[s];
    }
  }
  __syncthreads();
  if (tid<64){
    int o=tid, occ=o>>3, i=o&7;
    float s=0.f,q=0.f;
#pragma unroll
    for (int w=0;w<4;w++){ s+=WRED[((w*8+occ)*16+i)*2]; q+=WRED[((w*8+occ)*16+i)*2+1]; }
    part[(bi*64+o)*2]=s; part[(bi*64+o)*2+1]=q;
  }
}

// pass 2: linear read y1 -> bn1+relu -> L2 -> stats + store raw y2 in place
__global__ __launch_bounds__(256) void k_mlp2b(const float* __restrict__ w2,
                                               const float* __restrict__ b2,
                                               const float* __restrict__ ab1,
                                               float* __restrict__ part,
                                               float* __restrict__ y){
  __shared__ __align__(16) float L[9504];   // W2 4128 | XIN 4352 | WRED 1024
  float* W2  = L;
  float* XIN = L+4128;
  float* WRED= L+8480;
  const int tid=threadIdx.x, bi=blockIdx.x;
  const int row=tid>>3, oc=tid&7, wave=tid>>6;
  const int b=bi>>6, s0=(bi&63)*16;

  for (int i=tid;i<4096;i+=256){
    int r=i>>6, c=i&63;
    W2[r*64+((r>>3)<<2)+c]=w2[i];
  }
  float areg1[8],creg1[8],breg2[8];
#pragma unroll
  for (int i=0;i<8;i++){ int ch=oc*8+i; areg1[i]=ab1[ch*2]; creg1[i]=ab1[ch*2+1]; breg2[i]=b2[ch]; }
  float ps[8], pq[8];
#pragma unroll
  for (int s=0;s<8;s++){ ps[s]=0.f; pq[s]=0.f; }
  __syncthreads();

  for (int t=0; t<8; t++){
    int sgA = b*1024 + s0 + t*2, sgB = sgA+1;
    long baseA = ((long)sgA*32+row)*64 + oc*8;
    long baseB = ((long)sgB*32+row)*64 + oc*8;
    {
      f32x4 ya0=*(const f32x4*)(y+baseA), ya1=*(const f32x4*)(y+baseA+4);
      f32x4 yb0=*(const f32x4*)(y+baseB), yb1=*(const f32x4*)(y+baseB+4);
      f32x4 xo;
      xo[0]=fmaxf(fmaf(areg1[0],ya0[0],creg1[0]),0.0f);
      xo[1]=fmaxf(fmaf(areg1[1],ya0[1],creg1[1]),0.0f);
      xo[2]=fmaxf(fmaf(areg1[2],ya0[2],creg1[2]),0.0f);
      xo[3]=fmaxf(fmaf(areg1[3],ya0[3],creg1[3]),0.0f);
      *(f32x4*)(XIN+row*68+oc*8)=xo;
      xo[0]=fmaxf(fmaf(areg1[4],ya1[0],creg1[4]),0.0f);
      xo[1]=fmaxf(fmaf(areg1[5],ya1[1],creg1[5]),0.0f);
      xo[2]=fmaxf(fmaf(areg1[6],ya1[2],creg1[6]),0.0f);
      xo[3]=fmaxf(fmaf(areg1[7],ya1[3],creg1[7]),0.0f);
      *(f32x4*)(XIN+row*68+oc*8+4)=xo;
      xo[0]=fmaxf(fmaf(areg1[0],yb0[0],creg1[0]),0.0f);
      xo[1]=fmaxf(fmaf(areg1[1],yb0[1],creg1[1]),0.0f);
      xo[2]=fmaxf(fmaf(areg1[2],yb0[2],creg1[2]),0.0f);
      xo[3]=fmaxf(fmaf(areg1[3],yb0[3],creg1[3]),0.0f);
      *(f32x4*)(XIN+(row+32)*68+oc*8)=xo;
      xo[0]=fmaxf(fmaf(areg1[4],yb1[0],creg1[4]),0.0f);
      xo[1]=fmaxf(fmaf(areg1[5],yb1[1],creg1[5]),0.0f);
      xo[2]=fmaxf(fmaf(areg1[6],yb1[2],creg1[6]),0.0f);
      xo[3]=fmaxf(fmaf(areg1[7],yb1[3],creg1[7]),0.0f);
      *(f32x4*)(XIN+(row+32)*68+oc*8+4)=xo;
    }
    const float* x2A = XIN + row*68;
    const float* x2B = XIN + (row+32)*68;
    float acc2[2][8];
#pragma unroll
    for (int i=0;i<8;i++){ acc2[0][i]=breg2[i]; acc2[1][i]=breg2[i]; }
#pragma unroll
    for (int co=0;co<4;co++){
      f32x4 xa[4], xbv[4];
#pragma unroll
      for (int k=0;k<4;k++){ xa[k]=*(const f32x4*)(x2A+co*16+4*k); xbv[k]=*(const f32x4*)(x2B+co*16+4*k); }
#pragma unroll
      for (int i=0;i<8;i++)
        dot16x2(W2+(oc*8+i)*64+(oc<<2)+co*16, xa, xbv, acc2[0][i], acc2[1][i]);
    }
    // store raw y2 in place + stats
    *(f32x4*)(y+baseA)   = (f32x4){acc2[0][0],acc2[0][1],acc2[0][2],acc2[0][3]};
    *(f32x4*)(y+baseA+4) = (f32x4){acc2[0][4],acc2[0][5],acc2[0][6],acc2[0][7]};
    *(f32x4*)(y+baseB)   = (f32x4){acc2[1][0],acc2[1][1],acc2[1][2],acc2[1][3]};
    *(f32x4*)(y+baseB+4) = (f32x4){acc2[1][4],acc2[1][5],acc2[1][6],acc2[1][7]};
#pragma unroll
    for (int i=0;i<8;i++){
      ps[i]+=acc2[0][i]+acc2[1][i];
      pq[i]=fmaf(acc2[0][i],acc2[0][i],pq[i]); pq[i]=fmaf(acc2[1][i],acc2[1][i],pq[i]);
    }
  }
#pragma unroll
  for (int s=0;s<8;s++){
    ps[s]+=__shfl_xor(ps[s],8); ps[s]+=__shfl_xor(ps[s],16); ps[s]+=__shfl_xor(ps[s],32);
    pq[s]+=__shfl_xor(pq[s],8); pq[s]+=__shfl_xor(pq[s],16); pq[s]+=__shfl_xor(pq[s],32);
  }
  __syncthreads();
  if ((tid&63)<8){
    for (int s=0;s<8;s++){
      WRED[((wave*8+oc)*16+s)*2+0]=ps[s];
      WRED[((wave*8+oc)*16+s)*2+1]=pq[s];
    }
  }
  __syncthreads();
  if (tid<64){
    int o=tid, occ=o>>3, i=o&7;
    float s=0.f,q=0.f;
#pragma unroll
    for (int w=0;w<4;w++){ s+=WRED[((w*8+occ)*16+i)*2]; q+=WRED[((w*8+occ)*16+i)*2+1]; }
    part[(bi*64+o)*2]=s; part[(bi*64+o)*2+1]=q;
  }
}

// pass 3: linear read y2 -> bn2+relu -> L3 (full W3 staged once) -> stats + mx
__global__ __launch_bounds__(256) void k_mlp3b(const float* __restrict__ w3,
                                               const float* __restrict__ b3,
                                               const float* __restrict__ ab2,
                                               float* __restrict__ part,
                                               const float* __restrict__ y,
                                               float* __restrict__ mx){
  __shared__ __align__(16) float L[13696];  // W3F 8320 | XIN 4352 | WRED 1024
  float* W3F = L;
  float* XIN = L+8320;
  float* WRED= L+12672;
  const int tid=threadIdx.x, bi=blockIdx.x;
  const int row=tid>>3, oc=tid&7, wave=tid>>6;
  const int b=bi>>6, s0=(bi&63)*16;

  for (int i=tid;i<8192;i+=256){
    int og=i>>11, rem=i&2047, r=rem>>6, c=rem&63;
    W3F[og*2080 + r*64+((r>>2)<<2)+c]=w3[i];
  }
  float areg2[8],creg2[8];
#pragma unroll
  for (int i=0;i<8;i++){ int ch=oc*8+i; areg2[i]=ab2[ch*2]; creg2[i]=ab2[ch*2+1]; }
  float breg3[16];
#pragma unroll
  for (int og=0;og<4;og++)
#pragma unroll
    for (int i=0;i<4;i++) breg3[og*4+i]=b3[og*32+oc*4+i];
  float ps[16], pq[16];
#pragma unroll
  for (int s=0;s<16;s++){ ps[s]=0.f; pq[s]=0.f; }
  __syncthreads();

  for (int t=0; t<8; t++){
    int sgA = b*1024 + s0 + t*2, sgB = sgA+1;
    long baseA = ((long)sgA*32+row)*64 + oc*8;
    long baseB = ((long)sgB*32+row)*64 + oc*8;
    {
      f32x4 ya0=*(const f32x4*)(y+baseA), ya1=*(const f32x4*)(y+baseA+4);
      f32x4 yb0=*(const f32x4*)(y+baseB), yb1=*(const f32x4*)(y+baseB+4);
      f32x4 xo;
      xo[0]=fmaxf(fmaf(areg2[0],ya0[0],creg2[0]),0.0f);
      xo[1]=fmaxf(fmaf(areg2[1],ya0[1],creg2[1]),0.0f);
      xo[2]=fmaxf(fmaf(areg2[2],ya0[2],creg2[2]),0.0f);
      xo[3]=fmaxf(fmaf(areg2[3],ya0[3],creg2[3]),0.0f);
      *(f32x4*)(XIN+row*68+oc*8)=xo;
      xo[0]=fmaxf(fmaf(areg2[4],ya1[0],creg2[4]),0.0f);
      xo[1]=fmaxf(fmaf(areg2[5],ya1[1],creg2[5]),0.0f);
      xo[2]=fmaxf(fmaf(areg2[6],ya1[2],creg2[6]),0.0f);
      xo[3]=fmaxf(fmaf(areg2[7],ya1[3],creg2[7]),0.0f);
      *(f32x4*)(XIN+row*68+oc*8+4)=xo;
      xo[0]=fmaxf(fmaf(areg2[0],yb0[0],creg2[0]),0.0f);
      xo[1]=fmaxf(fmaf(areg2[1],yb0[1],creg2[1]),0.0f);
      xo[2]=fmaxf(fmaf(areg2[2],yb0[2],creg2[2]),0.0f);
      xo[3]=fmaxf(fmaf(areg2[3],yb0[3],creg2[3]),0.0f);
      *(f32x4*)(XIN+(row+32)*68+oc*8)=xo;
      xo[0]=fmaxf(fmaf(areg2[4],yb1[0],creg2[4]),0.0f);
      xo[1]=fmaxf(fmaf(areg2[5],yb1[1],creg2[5]),0.0f);
      xo[2]=fmaxf(fmaf(areg2[6],yb1[2],creg2[6]),0.0f);
      xo[3]=fmaxf(fmaf(areg2[7],yb1[3],creg2[7]),0.0f);
      *(f32x4*)(XIN+(row+32)*68+oc*8+4)=xo;
    }
    const float* x2A = XIN + row*68;
    const float* x2B = XIN + (row+32)*68;
    float acc3[4][2][4];
#pragma unroll
    for (int og=0;og<4;og++)
#pragma unroll
      for (int i=0;i<4;i++){ acc3[og][0][i]=breg3[og*4+i]; acc3[og][1][i]=breg3[og*4+i]; }
#pragma unroll
    for (int co=0;co<4;co++){
      f32x4 xa[4], xbv[4];
#pragma unroll
      for (int k=0;k<4;k++){ xa[k]=*(const f32x4*)(x2A+co*16+4*k); xbv[k]=*(const f32x4*)(x2B+co*16+4*k); }
#pragma unroll
      for (int og=0;og<4;og++)
#pragma unroll
        for (int i=0;i<4;i++)
          dot16x2(W3F+og*2080+(oc*4+i)*64+(oc<<2)+co*16, xa, xbv, acc3[og][0][i], acc3[og][1][i]);
    }
    float vm[2][16];
#pragma unroll
    for (int og=0;og<4;og++)
#pragma unroll
      for (int i=0;i<4;i++){
        int s=og*4+i;
        ps[s]+=acc3[og][0][i]+acc3[og][1][i];
        pq[s]=fmaf(acc3[og][0][i],acc3[og][0][i],pq[s]); pq[s]=fmaf(acc3[og][1][i],acc3[og][1][i],pq[s]);
        vm[0][s]=acc3[og][0][i]; vm[1][s]=acc3[og][1][i];
      }
    {
#pragma unroll
      for (int q=0;q<2;q++)
#pragma unroll
        for (int s=0;s<16;s++){
          vm[q][s]=fmaxf(vm[q][s],__shfl_xor(vm[q][s],8));
          vm[q][s]=fmaxf(vm[q][s],__shfl_xor(vm[q][s],16));
          vm[q][s]=fmaxf(vm[q][s],__shfl_xor(vm[q][s],32));
        }
      __syncthreads();   // previous tile's WRED readers done before overwrite
      if ((tid&63)<8){
#pragma unroll
        for (int q=0;q<2;q++)
#pragma unroll
          for (int s=0;s<16;s++) WRED[(q*32 + wave*8+oc)*16 + s]=vm[q][s];
      }
      __syncthreads();
      {
        int q=tid>>7, o=tid&127;
        int og=o>>5, occ=(o&31)>>2, s=og*4+(o&3);
        float v=WRED[(q*32 + 0*8+occ)*16+s];
        v=fmaxf(v,WRED[(q*32 + 1*8+occ)*16+s]);
        v=fmaxf(v,WRED[(q*32 + 2*8+occ)*16+s]);
        v=fmaxf(v,WRED[(q*32 + 3*8+occ)*16+s]);
        mx[(long)(q? sgB : sgA)*128+o]=v;
      }
    }
  }
  {
#pragma unroll
    for (int s=0;s<16;s++){
      ps[s]+=__shfl_xor(ps[s],8); ps[s]+=__shfl_xor(ps[s],16); ps[s]+=__shfl_xor(ps[s],32);
      pq[s]+=__shfl_xor(pq[s],8); pq[s]+=__shfl_xor(pq[s],16); pq[s]+=__shfl_xor(pq[s],32);
    }
    __syncthreads();
    if ((tid&63)<8){
      for (int s=0;s<16;s++){
        WRED[((wave*8+oc)*16+s)*2+0]=ps[s];
        WRED[((wave*8+oc)*16+s)*2+1]=pq[s];
      }
    }
    __syncthreads();
    if (tid<128){
      int o=tid, og=o>>5, occ=(o&31)>>2, i=o&3, s2=og*4+i;
      float s=0.f,q=0.f;
#pragma unroll
      for (int w=0;w<4;w++){ s+=WRED[((w*8+occ)*16+s2)*2]; q+=WRED[((w*8+occ)*16+s2)*2+1]; }
      part[(bi*128+o)*2]=s; part[(bi*128+o)*2+1]=q;
    }
  }
}

// ---------------------------------------------------------------- stats finalize
__global__ void k_red(const float* __restrict__ part,
                      const float* __restrict__ gam,
                      const float* __restrict__ bet,
                      float* __restrict__ ab, int nch, int nblk){
  __shared__ float red[4][128][2];
  const int tid=threadIdx.x, ch=tid%nch, seg=tid/nch;
  float s=0.f,q=0.f;
  for (int i=seg;i<nblk;i+=4){ s+=part[(i*nch+ch)*2]; q+=part[(i*nch+ch)*2+1]; }
  red[seg][ch][0]=s; red[seg][ch][1]=q;
  __syncthreads();
  if (seg==0){
    s=red[0][ch][0]+red[1][ch][0]+red[2][ch][0]+red[3][ch][0];
    q=red[0][ch][1]+red[1][ch][1]+red[2][ch][1]+red[3][ch][1];
    float mu=s*(1.0f/524288.0f);
    float var=q*(1.0f/524288.0f)-mu*mu;
    var=fmaxf(var,0.0f);
    float a=gam[ch]/sqrtf(var+1e-5f);
    float c=bet[ch]-mu*a;
    ab[ch*2]=a; ab[ch*2+1]=c;
  }
}

// ---------------------------------------------------------------- final: onp = relu(a3*mx + c3)
__global__ __launch_bounds__(256) void k_out(const float* __restrict__ mx,
                                             const float* __restrict__ ab3,
                                             float* __restrict__ onp){
  int i = (blockIdx.x*256 + threadIdx.x)*4;   // 2048 blocks x 256 x 4 = 2,097,152
  int ch = i & 127;
  f32x4 v = *(const f32x4*)(mx+i);
  f32x4 r;
  r[0]=fmaxf(fmaf(ab3[(ch+0)*2], v[0], ab3[(ch+0)*2+1]), 0.0f);
  r[1]=fmaxf(fmaf(ab3[(ch+1)*2], v[1], ab3[(ch+1)*2+1]), 0.0f);
  r[2]=fmaxf(fmaf(ab3[(ch+2)*2], v[2], ab3[(ch+2)*2+1]), 0.0f);
  r[3]=fmaxf(fmaf(ab3[(ch+3)*2], v[3], ab3[(ch+3)*2+1]), 0.0f);
  *(f32x4*)(onp+i)=r;
}

// ---------------------------------------------------------------- host
extern "C" void kernel_launch(void* const* d_in, const int* in_sizes, int n_in,
                              void* d_out, int out_size, void* d_ws, size_t ws_size,
                              hipStream_t stream){
  const float* xyz=(const float*)d_in[0];
  const float* pts=(const float*)d_in[1];
  const float* w1 =(const float*)d_in[2];
  const float* b1 =(const float*)d_in[3];
  const float* g1 =(const float*)d_in[4];
  const float* be1=(const float*)d_in[5];
  const float* w2 =(const float*)d_in[6];
  const float* b2 =(const float*)d_in[7];
  const float* g2 =(const float*)d_in[8];
  const float* be2=(const float*)d_in[9];
  const float* w3 =(const float*)d_in[10];
  const float* b3 =(const float*)d_in[11];
  const float* g3 =(const float*)d_in[12];
  const float* be3=(const float*)d_in[13];
  char* ws=(char*)d_ws;
  int*    cent=(int*)(ws);                 //       0
  ushort* kidx=(ushort*)(ws+  65536);      //  +1 MB
  float*  p   =(float*)(ws+ 1114112);      //  +1 MB (reused 3x)
  float*  ab1 =(float*)(ws+ 2162688);
  float*  ab2 =(float*)(ws+ 2163200);
  float*  ab3 =(float*)(ws+ 2163712);
  float*  mx  =(float*)(ws+ 2164736);      //  +8.4 MB -> end ~10.6 MB (proven)
  int*    flags=(int*)(ws+15728640);       //  64 B of flags at 15 MB
  float*  y   =(float*)(ws+16777216);      //  +128 MB (r19 proved present)
  float* oxyz=(float*)d_out;
  float* onp =oxyz + 16*1024*3;

  hipMemsetAsync(flags, 0, 64, stream);
  k_fk<<<512, 256, 0, stream>>>(xyz, cent, oxyz, kidx, flags);
  k_mlp1b<<<1024, 256, 0, stream>>>(xyz, pts, w1, b1, cent, kidx, p, y);
  k_red<<<1, 256, 0, stream>>>(p, g1, be1, ab1, 64, 1024);
  k_mlp2b<<<1024, 256, 0, stream>>>(w2, b2, ab1, p, y);
  k_red<<<1, 256, 0, stream>>>(p, g2, be2, ab2, 64, 1024);
  k_mlp3b<<<1024, 256, 0, stream>>>(w3, b3, ab2, p, y, mx);
  k_red<<<1, 512, 0, stream>>>(p, g3, be3, ab3, 128, 1024);
  k_out<<<2048, 256, 0, stream>>>(mx, ab3, onp);
}

// Round 12
// 2007.513 us; speedup vs baseline: 1.2693x; 1.2693x over previous
//
#include <hip/hip_runtime.h>

typedef unsigned int   uint;
typedef unsigned short ushort;
typedef unsigned long long u64;
typedef float f32x4 __attribute__((ext_vector_type(4)));

// weights loaded once (from LDS), applied to two rows
__device__ __forceinline__ void dot16x2(const float* __restrict__ wr,
                                        const f32x4* xa, const f32x4* xb,
                                        float& accA, float& accB){
#pragma unroll
  for (int k=0;k<4;k++){
    f32x4 w=*(const f32x4*)(wr+4*k);
    accA=fmaf(xa[k][0],w[0],accA); accA=fmaf(xa[k][1],w[1],accA);
    accA=fmaf(xa[k][2],w[2],accA); accA=fmaf(xa[k][3],w[3],accA);
    accB=fmaf(xb[k][0],w[0],accB); accB=fmaf(xb[k][1],w[1],accB);
    accB=fmaf(xb[k][2],w[2],accB); accB=fmaf(xb[k][3],w[3],accB);
  }
}

// ---------------------------------------------------------------- FPS fp32 (r13, measured best)
__global__ __launch_bounds__(256) void k_fps(const float* __restrict__ xyz,
                                             int* __restrict__ cent,
                                             float* __restrict__ oxyz){
  __shared__ __align__(16) float sp[4096][4];   // 64 KB
  __shared__ u64 rk[2][4];
  __shared__ int sel[1024];                     // 4 KB
  const int b = blockIdx.x, tid = threadIdx.x, lane=tid&63, wave=tid>>6;
  const float* xb = xyz + (long)b*4096*3;
  float px[16], py[16], pz[16], pd[16];
#pragma unroll
  for (int j=0;j<16;j++){
    int n = tid + 256*j;
    float x=xb[n*3], y=xb[n*3+1], z=xb[n*3+2];
    sp[n][0]=x; sp[n][1]=y; sp[n][2]=z; sp[n][3]=0.0f;
    px[j]=x; py[j]=y; pz[j]=z; pd[j]=1e10f;
  }
  if (tid==0) sel[0]=0;
  __syncthreads();
  int f = 0;
  for (int t=1;t<1024;t++){
    f32x4 c = *(const f32x4*)sp[f];
    float bv=-1.0f; int bi=0;
#pragma unroll
    for (int j=0;j<16;j++){
      int n = tid + 256*j;
      float dx=px[j]-c[0], dy=py[j]-c[1], dz=pz[j]-c[2];
      float d=__fadd_rn(__fadd_rn(__fmul_rn(dx,dx),__fmul_rn(dy,dy)),__fmul_rn(dz,dz));
      float mn=fminf(pd[j],d); pd[j]=mn;
      if (j==0){ bv=mn; bi=n; }
      else if (mn>bv){ bv=mn; bi=n; }
    }
    u64 key = ((u64)__float_as_uint(bv)<<32) | (uint)(~bi);
#pragma unroll
    for (int off=32;off;off>>=1){
      u64 ok=__shfl_xor(key,off);
      key = ok>key ? ok : key;
    }
    int par=t&1;
    if (lane==0) rk[par][wave]=key;
    __syncthreads();
    {
      u64 k0=rk[par][0], k1=rk[par][1], k2=rk[par][2], k3=rk[par][3];
      u64 ka = k0>k1?k0:k1;
      u64 kb = k2>k3?k2:k3;
      u64 kk = ka>kb?ka:kb;
      f = (int)(~(uint)kk) & 4095;
    }
    if (tid==0) sel[t]=f;
  }
  __syncthreads();
#pragma unroll
  for (int j=0;j<4;j++){
    int s = tid + 256*j;
    int n = sel[s];
    cent[b*1024+s]=n;
    f32x4 cf=*(const f32x4*)sp[n];
    oxyz[(b*1024+s)*3+0]=cf[0];
    oxyz[(b*1024+s)*3+1]=cf[1];
    oxyz[(b*1024+s)*3+2]=cf[2];
  }
}

// ---------------------------------------------------------------- KNN
// r22: un-fused (r21's fps+knn fusion cost +518us: zero overlap possible --
// knn's last chunk needs fps's last centroid -- and the 2-unit tail added a
// full unit). r21's arithmetic measured knn unit ~500us, ~70% of it the 32
// rounds x 6-level DEPENDENT u64 shfl butterfly (latency-bound ds_bpermute).
// Fix: interleave TWO queries per wave -- two independent butterfly chains
// pipeline through the LDS pipe (~2x), and the point-scan loop is shared
// (halves sx/sy/sz reads). Per-query op sequence identical -> bit-identical.
__global__ __launch_bounds__(256) void k_knn(const float* __restrict__ xyz,
                                             const int* __restrict__ cent,
                                             ushort* __restrict__ kidx){
  __shared__ float sx[4096], sy[4096], sz[4096];   // 48 KB
  const int bx=blockIdx.x, b=bx>>5, chunk=bx&31;
  const int tid=threadIdx.x, lane=tid&63, wave=tid>>6;
  const float* xb = xyz + (long)b*4096*3;
#pragma unroll
  for (int j=0;j<16;j++){
    int n = tid + 256*j;
    sx[n]=xb[n*3]; sy[n]=xb[n*3+1]; sz[n]=xb[n*3+2];
  }
  __syncthreads();
  const u64 SENT=~0ull;
  for (int qp=0; qp<4; qp++){
    int sA = chunk*32 + wave*8 + qp*2;
    int sB = sA + 1;
    int qnA = cent[b*1024 + sA] & 4095;
    int qnB = cent[b*1024 + sB] & 4095;
    double qxA=(double)sx[qnA], qyA=(double)sy[qnA], qzA=(double)sz[qnA];
    double qxB=(double)sx[qnB], qyB=(double)sy[qnB], qzB=(double)sz[qnB];
    u64 k1A=SENT, k2A=SENT, k1B=SENT, k2B=SENT;
    // shared scan: one point load feeds both queries' chains
#pragma unroll 4
    for (int j=0;j<64;j++){
      int n = lane + 64*j;
      double px=(double)sx[n], py=(double)sy[n], pz=(double)sz[n];
      double dxA=px-qxA, dyA=py-qyA, dzA=pz-qzA;
      double dxB=px-qxB, dyB=py-qyB, dzB=pz-qzB;
      double d2A = dxA*dxA + dyA*dyA + dzA*dzA;
      double d2B = dxB*dxB + dyB*dyB + dzB*dzB;
      u64 kdA = (((u64)__double_as_longlong(d2A)) & ~4095ull) | (uint)n;
      u64 kdB = (((u64)__double_as_longlong(d2B)) & ~4095ull) | (uint)n;
      if (kdA<k1A){ k2A=k1A; k1A=kdA; }
      else if (kdA<k2A){ k2A=kdA; }
      if (kdB<k1B){ k2B=k1B; k1B=kdB; }
      else if (kdB<k2B){ k2B=kdB; }
    }
    u64 removedA=0ull, removedB=0ull;
    ushort* outA = kidx + (b*1024 + sA)*32;
    ushort* outB = kidx + (b*1024 + sB)*32;
    for (int r=0;r<32;r++){
      u64 wkA=k1A, wkB=k1B;
#pragma unroll
      for (int off=32;off;off>>=1){
        u64 okA=__shfl_xor(wkA,off);
        u64 okB=__shfl_xor(wkB,off);
        wkA = okA<wkA ? okA : wkA;
        wkB = okB<wkB ? okB : wkB;
      }
      if (lane==0){ outA[r]=(ushort)(wkA & 4095u); outB[r]=(ushort)(wkB & 4095u); }
      if (wkA==k1A){
        removedA |= 1ull << (((uint)(k1A&4095u))>>6);
        if (k2A!=SENT){ k1A=k2A; k2A=SENT; }
        else {
          k1A=SENT; k2A=SENT;
#pragma unroll 4
          for (int j=0;j<64;j++){
            if ((removedA>>j)&1ull) continue;
            int n = lane + 64*j;
            double dx=(double)sx[n]-qxA, dy=(double)sy[n]-qyA, dz=(double)sz[n]-qzA;
            double d2 = dx*dx + dy*dy + dz*dz;
            u64 kd = (((u64)__double_as_longlong(d2)) & ~4095ull) | (uint)n;
            if (kd<k1A){ k2A=k1A; k1A=kd; }
            else if (kd<k2A){ k2A=kd; }
          }
        }
      }
      if (wkB==k1B){
        removedB |= 1ull << (((uint)(k1B&4095u))>>6);
        if (k2B!=SENT){ k1B=k2B; k2B=SENT; }
        else {
          k1B=SENT; k2B=SENT;
#pragma unroll 4
          for (int j=0;j<64;j++){
            if ((removedB>>j)&1ull) continue;
            int n = lane + 64*j;
            double dx=(double)sx[n]-qxB, dy=(double)sy[n]-qyB, dz=(double)sz[n]-qzB;
            double d2 = dx*dx + dy*dy + dz*dz;
            u64 kd = (((u64)__double_as_longlong(d2)) & ~4095ull) | (uint)n;
            if (kd<k1B){ k2B=k1B; k1B=kd; }
            else if (kd<k2B){ k2B=kd; }
          }
        }
      }
    }
  }
}

// ================================================================ MLP passes (r20, passing)
// pass 1: gather -> L1 -> stats + store raw y1
__global__ __launch_bounds__(256) void k_mlp1b(const float* __restrict__ xyz,
                                               const float* __restrict__ pts,
                                               const float* __restrict__ w1,
                                               const float* __restrict__ b1,
                                               const int* __restrict__ cent,
                                               const ushort* __restrict__ kidx,
                                               float* __restrict__ part,
                                               float* __restrict__ y){
  __shared__ __align__(16) float L[9760];   // W1 4384 | XIN 4352 | WRED 1024
  float* W1  = L;
  float* XIN = L+4384;
  float* WRED= L+8736;
  const int tid=threadIdx.x, bi=blockIdx.x;
  const int row=tid>>3, oc=tid&7, wave=tid>>6;
  const int b=bi>>6, s0=(bi&63)*16;
  const long bN=(long)b*4096;

  for (int i=tid;i<64*68;i+=256){
    int r=i/68, c=i-r*68;
    float v = (c<64)? w1[r*67+3+c] : (c<67? w1[r*67+(c-64)] : 0.0f);
    W1[r*68+((r>>3)<<2)+c]=v;
  }
  float breg1[8];
#pragma unroll
  for (int i=0;i<8;i++) breg1[i]=b1[oc*8+i];
  float ps[8], pq[8];
#pragma unroll
  for (int s=0;s<8;s++){ ps[s]=0.f; pq[s]=0.f; }
  __syncthreads();

  for (int t=0; t<8; t++){
    int sgA = b*1024 + s0 + t*2, sgB = sgA+1;
    {
      int nA = kidx[sgA*32+row] & 4095;
      int nB = kidx[sgB*32+row] & 4095;
      const float* prA = pts + (bN+nA)*64;
      const float* prB = pts + (bN+nB)*64;
      *(f32x4*)(XIN + row*68 + oc*8)          = *(const f32x4*)(prA + oc*8);
      *(f32x4*)(XIN + row*68 + oc*8 + 4)      = *(const f32x4*)(prA + oc*8 + 4);
      *(f32x4*)(XIN + (row+32)*68 + oc*8)     = *(const f32x4*)(prB + oc*8);
      *(f32x4*)(XIN + (row+32)*68 + oc*8 + 4) = *(const f32x4*)(prB + oc*8 + 4);
      if (oc==0){
        int qA = cent[sgA] & 4095, qB = cent[sgB] & 4095;
        const float* xpA = xyz + (bN+nA)*3; const float* qpA = xyz + (bN+qA)*3;
        const float* xpB = xyz + (bN+nB)*3; const float* qpB = xyz + (bN+qB)*3;
        XIN[row*68+64]=xpA[0]-qpA[0]; XIN[row*68+65]=xpA[1]-qpA[1];
        XIN[row*68+66]=xpA[2]-qpA[2]; XIN[row*68+67]=0.0f;
        XIN[(row+32)*68+64]=xpB[0]-qpB[0]; XIN[(row+32)*68+65]=xpB[1]-qpB[1];
        XIN[(row+32)*68+66]=xpB[2]-qpB[2]; XIN[(row+32)*68+67]=0.0f;
      }
    }
    const float* xrowA = XIN + row*68;
    const float* xrowB = XIN + (row+32)*68;
    float acc[2][8];
#pragma unroll
    for (int i=0;i<8;i++){ acc[0][i]=breg1[i]; acc[1][i]=breg1[i]; }
#pragma unroll
    for (int co=0;co<4;co++){
      f32x4 xa[4], xbv[4];
#pragma unroll
      for (int k=0;k<4;k++){ xa[k]=*(const f32x4*)(xrowA+co*16+4*k); xbv[k]=*(const f32x4*)(xrowB+co*16+4*k); }
#pragma unroll
      for (int i=0;i<8;i++)
        dot16x2(W1+(oc*8+i)*68+(oc<<2)+co*16, xa, xbv, acc[0][i], acc[1][i]);
    }
    {
      f32x4 xtA=*(const f32x4*)(xrowA+64), xtB=*(const f32x4*)(xrowB+64);
#pragma unroll
      for (int i=0;i<8;i++){
        const float* wr=W1+(oc*8+i)*68+(oc<<2)+64;
        f32x4 w=*(const f32x4*)wr;
        acc[0][i]=fmaf(xtA[0],w[0],acc[0][i]); acc[0][i]=fmaf(xtA[1],w[1],acc[0][i]);
        acc[0][i]=fmaf(xtA[2],w[2],acc[0][i]); acc[0][i]=fmaf(xtA[3],w[3],acc[0][i]);
        acc[1][i]=fmaf(xtB[0],w[0],acc[1][i]); acc[1][i]=fmaf(xtB[1],w[1],acc[1][i]);
        acc[1][i]=fmaf(xtB[2],w[2],acc[1][i]); acc[1][i]=fmaf(xtB[3],w[3],acc[1][i]);
      }
    }
    // store raw y1 + stats
    {
      long baseA = ((long)sgA*32+row)*64 + oc*8;
      long baseB = ((long)sgB*32+row)*64 + oc*8;
      *(f32x4*)(y+baseA)   = (f32x4){acc[0][0],acc[0][1],acc[0][2],acc[0][3]};
      *(f32x4*)(y+baseA+4) = (f32x4){acc[0][4],acc[0][5],acc[0][6],acc[0][7]};
      *(f32x4*)(y+baseB)   = (f32x4){acc[1][0],acc[1][1],acc[1][2],acc[1][3]};
      *(f32x4*)(y+baseB+4) = (f32x4){acc[1][4],acc[1][5],acc[1][6],acc[1][7]};
    }
#pragma unroll
    for (int i=0;i<8;i++){
      ps[i]+=acc[0][i]+acc[1][i];
      pq[i]=fmaf(acc[0][i],acc[0][i],pq[i]); pq[i]=fmaf(acc[1][i],acc[1][i],pq[i]);
    }
  }
#pragma unroll
  for (int s=0;s<8;s++){
    ps[s]+=__shfl_xor(ps[s],8); ps[s]+=__shfl_xor(ps[s],16); ps[s]+=__shfl_xor(ps[s],32);
    pq[s]+=__shfl_xor(pq[s],8); pq[s]+=__shfl_xor(pq[s],16); pq[s]+=__shfl_xor(pq[s],32);
  }
  __syncthreads();
  if ((tid&63)<8){
    for (int s=0;s<8;s++){
      WRED[((wave*8+oc)*16+s)*2+0]=ps[s];
      WRED[((wave*8+oc)*16+s)*2+1]=pq[s];
    }
  }
  __syncthreads();
  if (tid<64){
    int o=tid, occ=o>>3, i=o&7;
    float s=0.f,q=0.f;
#pragma unroll
    for (int w=0;w<4;w++){ s+=WRED[((w*8+occ)*16+i)*2]; q+=WRED[((w*8+occ)*16+i)*2+1]; }
    part[(bi*64+o)*2]=s; part[(bi*64+o)*2+1]=q;
  }
}

// pass 2: linear read y1 -> bn1+relu -> L2 -> stats + store raw y2 in place
__global__ __launch_bounds__(256) void k_mlp2b(const float* __restrict__ w2,
                                               const float* __restrict__ b2,
                                               const float* __restrict__ ab1,
                                               float* __restrict__ part,
                                               float* __restrict__ y){
  __shared__ __align__(16) float L[9504];   // W2 4128 | XIN 4352 | WRED 1024
  float* W2  = L;
  float* XIN = L+4128;
  float* WRED= L+8480;
  const int tid=threadIdx.x, bi=blockIdx.x;
  const int row=tid>>3, oc=tid&7, wave=tid>>6;
  const int b=bi>>6, s0=(bi&63)*16;

  for (int i=tid;i<4096;i+=256){
    int r=i>>6, c=i&63;
    W2[r*64+((r>>3)<<2)+c]=w2[i];
  }
  float areg1[8],creg1[8],breg2[8];
#pragma unroll
  for (int i=0;i<8;i++){ int ch=oc*8+i; areg1[i]=ab1[ch*2]; creg1[i]=ab1[ch*2+1]; breg2[i]=b2[ch]; }
  float ps[8], pq[8];
#pragma unroll
  for (int s=0;s<8;s++){ ps[s]=0.f; pq[s]=0.f; }
  __syncthreads();

  for (int t=0; t<8; t++){
    int sgA = b*1024 + s0 + t*2, sgB = sgA+1;
    long baseA = ((long)sgA*32+row)*64 + oc*8;
    long baseB = ((long)sgB*32+row)*64 + oc*8;
    {
      f32x4 ya0=*(const f32x4*)(y+baseA), ya1=*(const f32x4*)(y+baseA+4);
      f32x4 yb0=*(const f32x4*)(y+baseB), yb1=*(const f32x4*)(y+baseB+4);
      f32x4 xo;
      xo[0]=fmaxf(fmaf(areg1[0],ya0[0],creg1[0]),0.0f);
      xo[1]=fmaxf(fmaf(areg1[1],ya0[1],creg1[1]),0.0f);
      xo[2]=fmaxf(fmaf(areg1[2],ya0[2],creg1[2]),0.0f);
      xo[3]=fmaxf(fmaf(areg1[3],ya0[3],creg1[3]),0.0f);
      *(f32x4*)(XIN+row*68+oc*8)=xo;
      xo[0]=fmaxf(fmaf(areg1[4],ya1[0],creg1[4]),0.0f);
      xo[1]=fmaxf(fmaf(areg1[5],ya1[1],creg1[5]),0.0f);
      xo[2]=fmaxf(fmaf(areg1[6],ya1[2],creg1[6]),0.0f);
      xo[3]=fmaxf(fmaf(areg1[7],ya1[3],creg1[7]),0.0f);
      *(f32x4*)(XIN+row*68+oc*8+4)=xo;
      xo[0]=fmaxf(fmaf(areg1[0],yb0[0],creg1[0]),0.0f);
      xo[1]=fmaxf(fmaf(areg1[1],yb0[1],creg1[1]),0.0f);
      xo[2]=fmaxf(fmaf(areg1[2],yb0[2],creg1[2]),0.0f);
      xo[3]=fmaxf(fmaf(areg1[3],yb0[3],creg1[3]),0.0f);
      *(f32x4*)(XIN+(row+32)*68+oc*8)=xo;
      xo[0]=fmaxf(fmaf(areg1[4],yb1[0],creg1[4]),0.0f);
      xo[1]=fmaxf(fmaf(areg1[5],yb1[1],creg1[5]),0.0f);
      xo[2]=fmaxf(fmaf(areg1[6],yb1[2],creg1[6]),0.0f);
      xo[3]=fmaxf(fmaf(areg1[7],yb1[3],creg1[7]),0.0f);
      *(f32x4*)(XIN+(row+32)*68+oc*8+4)=xo;
    }
    const float* x2A = XIN + row*68;
    const float* x2B = XIN + (row+32)*68;
    float acc2[2][8];
#pragma unroll
    for (int i=0;i<8;i++){ acc2[0][i]=breg2[i]; acc2[1][i]=breg2[i]; }
#pragma unroll
    for (int co=0;co<4;co++){
      f32x4 xa[4], xbv[4];
#pragma unroll
      for (int k=0;k<4;k++){ xa[k]=*(const f32x4*)(x2A+co*16+4*k); xbv[k]=*(const f32x4*)(x2B+co*16+4*k); }
#pragma unroll
      for (int i=0;i<8;i++)
        dot16x2(W2+(oc*8+i)*64+(oc<<2)+co*16, xa, xbv, acc2[0][i], acc2[1][i]);
    }
    // store raw y2 in place + stats
    *(f32x4*)(y+baseA)   = (f32x4){acc2[0][0],acc2[0][1],acc2[0][2],acc2[0][3]};
    *(f32x4*)(y+baseA+4) = (f32x4){acc2[0][4],acc2[0][5],acc2[0][6],acc2[0][7]};
    *(f32x4*)(y+baseB)   = (f32x4){acc2[1][0],acc2[1][1],acc2[1][2],acc2[1][3]};
    *(f32x4*)(y+baseB+4) = (f32x4){acc2[1][4],acc2[1][5],acc2[1][6],acc2[1][7]};
#pragma unroll
    for (int i=0;i<8;i++){
      ps[i]+=acc2[0][i]+acc2[1][i];
      pq[i]=fmaf(acc2[0][i],acc2[0][i],pq[i]); pq[i]=fmaf(acc2[1][i],acc2[1][i],pq[i]);
    }
  }
#pragma unroll
  for (int s=0;s<8;s++){
    ps[s]+=__shfl_xor(ps[s],8); ps[s]+=__shfl_xor(ps[s],16); ps[s]+=__shfl_xor(ps[s],32);
    pq[s]+=__shfl_xor(pq[s],8); pq[s]+=__shfl_xor(pq[s],16); pq[s]+=__shfl_xor(pq[s],32);
  }
  __syncthreads();
  if ((tid&63)<8){
    for (int s=0;s<8;s++){
      WRED[((wave*8+oc)*16+s)*2+0]=ps[s];
      WRED[((wave*8+oc)*16+s)*2+1]=pq[s];
    }
  }
  __syncthreads();
  if (tid<64){
    int o=tid, occ=o>>3, i=o&7;
    float s=0.f,q=0.f;
#pragma unroll
    for (int w=0;w<4;w++){ s+=WRED[((w*8+occ)*16+i)*2]; q+=WRED[((w*8+occ)*16+i)*2+1]; }
    part[(bi*64+o)*2]=s; part[(bi*64+o)*2+1]=q;
  }
}

// pass 3: linear read y2 -> bn2+relu -> L3 (full W3 staged once) -> stats + mx
__global__ __launch_bounds__(256) void k_mlp3b(const float* __restrict__ w3,
                                               const float* __restrict__ b3,
                                               const float* __restrict__ ab2,
                                               float* __restrict__ part,
                                               const float* __restrict__ y,
                                               float* __restrict__ mx){
  __shared__ __align__(16) float L[13696];  // W3F 8320 | XIN 4352 | WRED 1024
  float* W3F = L;
  float* XIN = L+8320;
  float* WRED= L+12672;
  const int tid=threadIdx.x, bi=blockIdx.x;
  const int row=tid>>3, oc=tid&7, wave=tid>>6;
  const int b=bi>>6, s0=(bi&63)*16;

  for (int i=tid;i<8192;i+=256){
    int og=i>>11, rem=i&2047, r=rem>>6, c=rem&63;
    W3F[og*2080 + r*64+((r>>2)<<2)+c]=w3[i];
  }
  float areg2[8],creg2[8];
#pragma unroll
  for (int i=0;i<8;i++){ int ch=oc*8+i; areg2[i]=ab2[ch*2]; creg2[i]=ab2[ch*2+1]; }
  float breg3[16];
#pragma unroll
  for (int og=0;og<4;og++)
#pragma unroll
    for (int i=0;i<4;i++) breg3[og*4+i]=b3[og*32+oc*4+i];
  float ps[16], pq[16];
#pragma unroll
  for (int s=0;s<16;s++){ ps[s]=0.f; pq[s]=0.f; }
  __syncthreads();

  for (int t=0; t<8; t++){
    int sgA = b*1024 + s0 + t*2, sgB = sgA+1;
    long baseA = ((long)sgA*32+row)*64 + oc*8;
    long baseB = ((long)sgB*32+row)*64 + oc*8;
    {
      f32x4 ya0=*(const f32x4*)(y+baseA), ya1=*(const f32x4*)(y+baseA+4);
      f32x4 yb0=*(const f32x4*)(y+baseB), yb1=*(const f32x4*)(y+baseB+4);
      f32x4 xo;
      xo[0]=fmaxf(fmaf(areg2[0],ya0[0],creg2[0]),0.0f);
      xo[1]=fmaxf(fmaf(areg2[1],ya0[1],creg2[1]),0.0f);
      xo[2]=fmaxf(fmaf(areg2[2],ya0[2],creg2[2]),0.0f);
      xo[3]=fmaxf(fmaf(areg2[3],ya0[3],creg2[3]),0.0f);
      *(f32x4*)(XIN+row*68+oc*8)=xo;
      xo[0]=fmaxf(fmaf(areg2[4],ya1[0],creg2[4]),0.0f);
      xo[1]=fmaxf(fmaf(areg2[5],ya1[1],creg2[5]),0.0f);
      xo[2]=fmaxf(fmaf(areg2[6],ya1[2],creg2[6]),0.0f);
      xo[3]=fmaxf(fmaf(areg2[7],ya1[3],creg2[7]),0.0f);
      *(f32x4*)(XIN+row*68+oc*8+4)=xo;
      xo[0]=fmaxf(fmaf(areg2[0],yb0[0],creg2[0]),0.0f);
      xo[1]=fmaxf(fmaf(areg2[1],yb0[1],creg2[1]),0.0f);
      xo[2]=fmaxf(fmaf(areg2[2],yb0[2],creg2[2]),0.0f);
      xo[3]=fmaxf(fmaf(areg2[3],yb0[3],creg2[3]),0.0f);
      *(f32x4*)(XIN+(row+32)*68+oc*8)=xo;
      xo[0]=fmaxf(fmaf(areg2[4],yb1[0],creg2[4]),0.0f);
      xo[1]=fmaxf(fmaf(areg2[5],yb1[1],creg2[5]),0.0f);
      xo[2]=fmaxf(fmaf(areg2[6],yb1[2],creg2[6]),0.0f);
      xo[3]=fmaxf(fmaf(areg2[7],yb1[3],creg2[7]),0.0f);
      *(f32x4*)(XIN+(row+32)*68+oc*8+4)=xo;
    }
    const float* x2A = XIN + row*68;
    const float* x2B = XIN + (row+32)*68;
    float acc3[4][2][4];
#pragma unroll
    for (int og=0;og<4;og++)
#pragma unroll
      for (int i=0;i<4;i++){ acc3[og][0][i]=breg3[og*4+i]; acc3[og][1][i]=breg3[og*4+i]; }
#pragma unroll
    for (int co=0;co<4;co++){
      f32x4 xa[4], xbv[4];
#pragma unroll
      for (int k=0;k<4;k++){ xa[k]=*(const f32x4*)(x2A+co*16+4*k); xbv[k]=*(const f32x4*)(x2B+co*16+4*k); }
#pragma unroll
      for (int og=0;og<4;og++)
#pragma unroll
        for (int i=0;i<4;i++)
          dot16x2(W3F+og*2080+(oc*4+i)*64+(oc<<2)+co*16, xa, xbv, acc3[og][0][i], acc3[og][1][i]);
    }
    float vm[2][16];
#pragma unroll
    for (int og=0;og<4;og++)
#pragma unroll
      for (int i=0;i<4;i++){
        int s=og*4+i;
        ps[s]+=acc3[og][0][i]+acc3[og][1][i];
        pq[s]=fmaf(acc3[og][0][i],acc3[og][0][i],pq[s]); pq[s]=fmaf(acc3[og][1][i],acc3[og][1][i],pq[s]);
        vm[0][s]=acc3[og][0][i]; vm[1][s]=acc3[og][1][i];
      }
    {
#pragma unroll
      for (int q=0;q<2;q++)
#pragma unroll
        for (int s=0;s<16;s++){
          vm[q][s]=fmaxf(vm[q][s],__shfl_xor(vm[q][s],8));
          vm[q][s]=fmaxf(vm[q][s],__shfl_xor(vm[q][s],16));
          vm[q][s]=fmaxf(vm[q][s],__shfl_xor(vm[q][s],32));
        }
      __syncthreads();   // previous tile's WRED readers done before overwrite
      if ((tid&63)<8){
#pragma unroll
        for (int q=0;q<2;q++)
#pragma unroll
          for (int s=0;s<16;s++) WRED[(q*32 + wave*8+oc)*16 + s]=vm[q][s];
      }
      __syncthreads();
      {
        int q=tid>>7, o=tid&127;
        int og=o>>5, occ=(o&31)>>2, s=og*4+(o&3);
        float v=WRED[(q*32 + 0*8+occ)*16+s];
        v=fmaxf(v,WRED[(q*32 + 1*8+occ)*16+s]);
        v=fmaxf(v,WRED[(q*32 + 2*8+occ)*16+s]);
        v=fmaxf(v,WRED[(q*32 + 3*8+occ)*16+s]);
        mx[(long)(q? sgB : sgA)*128+o]=v;
      }
    }
  }
  {
#pragma unroll
    for (int s=0;s<16;s++){
      ps[s]+=__shfl_xor(ps[s],8); ps[s]+=__shfl_xor(ps[s],16); ps[s]+=__shfl_xor(ps[s],32);
      pq[s]+=__shfl_xor(pq[s],8); pq[s]+=__shfl_xor(pq[s],16); pq[s]+=__shfl_xor(pq[s],32);
    }
    __syncthreads();
    if ((tid&63)<8){
      for (int s=0;s<16;s++){
        WRED[((wave*8+oc)*16+s)*2+0]=ps[s];
        WRED[((wave*8+oc)*16+s)*2+1]=pq[s];
      }
    }
    __syncthreads();
    if (tid<128){
      int o=tid, og=o>>5, occ=(o&31)>>2, i=o&3, s2=og*4+i;
      float s=0.f,q=0.f;
#pragma unroll
      for (int w=0;w<4;w++){ s+=WRED[((w*8+occ)*16+s2)*2]; q+=WRED[((w*8+occ)*16+s2)*2+1]; }
      part[(bi*128+o)*2]=s; part[(bi*128+o)*2+1]=q;
    }
  }
}

// ---------------------------------------------------------------- stats finalize
__global__ void k_red(const float* __restrict__ part,
                      const float* __restrict__ gam,
                      const float* __restrict__ bet,
                      float* __restrict__ ab, int nch, int nblk){
  __shared__ float red[4][128][2];
  const int tid=threadIdx.x, ch=tid%nch, seg=tid/nch;
  float s=0.f,q=0.f;
  for (int i=seg;i<nblk;i+=4){ s+=part[(i*nch+ch)*2]; q+=part[(i*nch+ch)*2+1]; }
  red[seg][ch][0]=s; red[seg][ch][1]=q;
  __syncthreads();
  if (seg==0){
    s=red[0][ch][0]+red[1][ch][0]+red[2][ch][0]+red[3][ch][0];
    q=red[0][ch][1]+red[1][ch][1]+red[2][ch][1]+red[3][ch][1];
    float mu=s*(1.0f/524288.0f);
    float var=q*(1.0f/524288.0f)-mu*mu;
    var=fmaxf(var,0.0f);
    float a=gam[ch]/sqrtf(var+1e-5f);
    float c=bet[ch]-mu*a;
    ab[ch*2]=a; ab[ch*2+1]=c;
  }
}

// ---------------------------------------------------------------- final: onp = relu(a3*mx + c3)
__global__ __launch_bounds__(256) void k_out(const float* __restrict__ mx,
                                             const float* __restrict__ ab3,
                                             float* __restrict__ onp){
  int i = (blockIdx.x*256 + threadIdx.x)*4;   // 2048 blocks x 256 x 4 = 2,097,152
  int ch = i & 127;
  f32x4 v = *(const f32x4*)(mx+i);
  f32x4 r;
  r[0]=fmaxf(fmaf(ab3[(ch+0)*2], v[0], ab3[(ch+0)*2+1]), 0.0f);
  r[1]=fmaxf(fmaf(ab3[(ch+1)*2], v[1], ab3[(ch+1)*2+1]), 0.0f);
  r[2]=fmaxf(fmaf(ab3[(ch+2)*2], v[2], ab3[(ch+2)*2+1]), 0.0f);
  r[3]=fmaxf(fmaf(ab3[(ch+3)*2], v[3], ab3[(ch+3)*2+1]), 0.0f);
  *(f32x4*)(onp+i)=r;
}

// ---------------------------------------------------------------- host
extern "C" void kernel_launch(void* const* d_in, const int* in_sizes, int n_in,
                              void* d_out, int out_size, void* d_ws, size_t ws_size,
                              hipStream_t stream){
  const float* xyz=(const float*)d_in[0];
  const float* pts=(const float*)d_in[1];
  const float* w1 =(const float*)d_in[2];
  const float* b1 =(const float*)d_in[3];
  const float* g1 =(const float*)d_in[4];
  const float* be1=(const float*)d_in[5];
  const float* w2 =(const float*)d_in[6];
  const float* b2 =(const float*)d_in[7];
  const float* g2 =(const float*)d_in[8];
  const float* be2=(const float*)d_in[9];
  const float* w3 =(const float*)d_in[10];
  const float* b3 =(const float*)d_in[11];
  const float* g3 =(const float*)d_in[12];
  const float* be3=(const float*)d_in[13];
  char* ws=(char*)d_ws;
  int*    cent=(int*)(ws);                 //       0
  ushort* kidx=(ushort*)(ws+  65536);      //  +1 MB
  float*  p   =(float*)(ws+ 1114112);      //  +1 MB (reused 3x)
  float*  ab1 =(float*)(ws+ 2162688);
  float*  ab2 =(float*)(ws+ 2163200);
  float*  ab3 =(float*)(ws+ 2163712);
  float*  mx  =(float*)(ws+ 2164736);      //  +8.4 MB -> end ~10.6 MB (proven)
  float*  y   =(float*)(ws+16777216);      //  +128 MB (r19 proved present)
  float* oxyz=(float*)d_out;
  float* onp =oxyz + 16*1024*3;

  k_fps<<<16, 256, 0, stream>>>(xyz, cent, oxyz);
  k_knn<<<512, 256, 0, stream>>>(xyz, cent, kidx);
  k_mlp1b<<<1024, 256, 0, stream>>>(xyz, pts, w1, b1, cent, kidx, p, y);
  k_red<<<1, 256, 0, stream>>>(p, g1, be1, ab1, 64, 1024);
  k_mlp2b<<<1024, 256, 0, stream>>>(w2, b2, ab1, p, y);
  k_red<<<1, 256, 0, stream>>>(p, g2, be2, ab2, 64, 1024);
  k_mlp3b<<<1024, 256, 0, stream>>>(w3, b3, ab2, p, y, mx);
  k_red<<<1, 512, 0, stream>>>(p, g3, be3, ab3, 128, 1024);
  k_out<<<2048, 256, 0, stream>>>(mx, ab3, onp);
}